// Round 1
// baseline (126.773 us; speedup 1.0000x reference)
//
#include <hip/hip_runtime.h>

// SememeEmbeddingKNN:
//   emb      [V=50257, H=1024] f32
//   word_ids [L=256, W=16]     i32
//   sem_ids  [L=256, W=16, S=32] i32
//   out      [L, H] f32
// Per (l,w): dist2[s] = ||emb[sid[s]] - emb[wid]||^2 ; pick 3 LARGEST
// (ties -> smaller index, like jax.lax.top_k); out[l] += (0.5*(mean3 + w))/16.

#define HDIM 1024
#define SNUM 32
#define KNN  3

__global__ __launch_bounds__(256) void sememe_knn_kernel(
    const float* __restrict__ emb,
    const int*   __restrict__ word_ids,
    const int*   __restrict__ sem_ids,
    float*       __restrict__ out)
{
    const int b    = blockIdx.x;       // b = l*16 + w
    const int l    = b >> 4;
    const int t    = threadIdx.x;      // 0..255, owns float4 at h = 4t
    const int lane = t & 63;
    const int wave = t >> 6;

    __shared__ int   s_sid[SNUM];
    __shared__ float s_part[SNUM][4];
    __shared__ float s_dist[SNUM];
    __shared__ int   s_sel[KNN];

    const int wid = word_ids[b];
    if (t < SNUM) s_sid[t] = sem_ids[(size_t)b * SNUM + t];
    __syncthreads();

    const float4 wv = *reinterpret_cast<const float4*>(emb + (size_t)wid * HDIM + 4 * t);

    // Pass 1: 32 squared distances, block-reduced.
    for (int s = 0; s < SNUM; ++s) {
        const float4 sv = *reinterpret_cast<const float4*>(emb + (size_t)s_sid[s] * HDIM + 4 * t);
        const float dx = sv.x - wv.x;
        const float dy = sv.y - wv.y;
        const float dz = sv.z - wv.z;
        const float dw = sv.w - wv.w;
        float d = (dx * dx + dy * dy) + (dz * dz + dw * dw);
        #pragma unroll
        for (int off = 32; off >= 1; off >>= 1)
            d += __shfl_xor(d, off, 64);
        if (lane == 0) s_part[s][wave] = d;
    }
    __syncthreads();
    if (t < SNUM)
        s_dist[t] = (s_part[t][0] + s_part[t][1]) + (s_part[t][2] + s_part[t][3]);
    __syncthreads();

    // Top-3 by descending distance; strict '>' keeps the earliest index on
    // ties, matching jax.lax.top_k / torch.sort(stable descending) semantics.
    if (t == 0) {
        unsigned chosen = 0;
        for (int k = 0; k < KNN; ++k) {
            float best = -1.0f;
            int   bi   = 0;
            for (int s = 0; s < SNUM; ++s) {
                if (chosen & (1u << s)) continue;
                if (s_dist[s] > best) { best = s_dist[s]; bi = s; }
            }
            chosen |= (1u << bi);
            s_sel[k] = bi;
        }
    }
    __syncthreads();

    // Pass 2: gather the 3 selected rows (L2/L3-warm) and accumulate.
    const float4 e0 = *reinterpret_cast<const float4*>(emb + (size_t)s_sid[s_sel[0]] * HDIM + 4 * t);
    const float4 e1 = *reinterpret_cast<const float4*>(emb + (size_t)s_sid[s_sel[1]] * HDIM + 4 * t);
    const float4 e2 = *reinterpret_cast<const float4*>(emb + (size_t)s_sid[s_sel[2]] * HDIM + 4 * t);

    const float third = 1.0f / 3.0f;
    const float half  = 0.5f;
    const float invw  = 1.0f / 16.0f;

    const float ox = ((e0.x + e1.x + e2.x) * third + wv.x) * half * invw;
    const float oy = ((e0.y + e1.y + e2.y) * third + wv.y) * half * invw;
    const float oz = ((e0.z + e1.z + e2.z) * third + wv.z) * half * invw;
    const float ow = ((e0.w + e1.w + e2.w) * third + wv.w) * half * invw;

    float* op = out + (size_t)l * HDIM + 4 * t;
    atomicAdd(op + 0, ox);
    atomicAdd(op + 1, oy);
    atomicAdd(op + 2, oz);
    atomicAdd(op + 3, ow);
}

extern "C" void kernel_launch(void* const* d_in, const int* in_sizes, int n_in,
                              void* d_out, int out_size, void* d_ws, size_t ws_size,
                              hipStream_t stream) {
    const float* emb  = (const float*)d_in[0];
    const int*   wids = (const int*)d_in[1];
    const int*   sids = (const int*)d_in[2];
    float*       out  = (float*)d_out;

    const int n_words = in_sizes[1];   // L*W = 4096 workgroups

    hipMemsetAsync(d_out, 0, (size_t)out_size * sizeof(float), stream);
    sememe_knn_kernel<<<dim3(n_words), dim3(256), 0, stream>>>(emb, wids, sids, out);
}

// Round 2
// 112.702 us; speedup vs baseline: 1.1249x; 1.1249x over previous
//
#include <hip/hip_runtime.h>

// SememeEmbeddingKNN:
//   emb      [V=50257, H=1024] f32
//   word_ids [L=256, W=16]     i32
//   sem_ids  [L=256, W=16, S=32] i32
//   out      [L, H] f32
// Per (l,w): dist2[s] = ||emb[sid[s]] - emb[wid]||^2 ; pick 3 LARGEST
// (ties -> smaller index, like jax.lax.top_k); out[l] += (0.5*(mean3 + w))/16.
//
// R1 -> R2: latency-bound fix. Fully unroll the 32 gather+diff^2 loop into
// per-thread dpart[32] (static indices -> registers, 32 independent float4
// loads in flight per wave) and run the 32 shuffle-reduce chains afterwards
// (independent chains pipeline). VGPR 16 -> ~180 is the intended trade.

#define HDIM 1024
#define SNUM 32
#define KNN  3

__global__ __launch_bounds__(256) void sememe_knn_kernel(
    const float* __restrict__ emb,
    const int*   __restrict__ word_ids,
    const int*   __restrict__ sem_ids,
    float*       __restrict__ out)
{
    const int b    = blockIdx.x;       // b = l*16 + w
    const int l    = b >> 4;
    const int t    = threadIdx.x;      // 0..255, owns float4 at h = 4t
    const int lane = t & 63;
    const int wave = t >> 6;

    __shared__ int   s_sid[SNUM];
    __shared__ float s_part[SNUM][4];
    __shared__ float s_dist[SNUM];
    __shared__ int   s_sel[KNN];

    if (t < SNUM) s_sid[t] = sem_ids[(size_t)b * SNUM + t];
    const int wid = word_ids[b];
    __syncthreads();

    const float4 wv = *reinterpret_cast<const float4*>(emb + (size_t)wid * HDIM + 4 * t);

    // Pass 1a: 32 independent gathers + per-thread partial dist^2.
    float dpart[SNUM];
    #pragma unroll
    for (int s = 0; s < SNUM; ++s) {
        const float4 sv = *reinterpret_cast<const float4*>(emb + (size_t)s_sid[s] * HDIM + 4 * t);
        const float dx = sv.x - wv.x;
        const float dy = sv.y - wv.y;
        const float dz = sv.z - wv.z;
        const float dw = sv.w - wv.w;
        dpart[s] = (dx * dx + dy * dy) + (dz * dz + dw * dw);
    }

    // Pass 1b: 32 independent 6-deep shuffle-reduce chains (pipelined).
    #pragma unroll
    for (int s = 0; s < SNUM; ++s) {
        float d = dpart[s];
        #pragma unroll
        for (int off = 32; off >= 1; off >>= 1)
            d += __shfl_xor(d, off, 64);
        if (lane == 0) s_part[s][wave] = d;
    }
    __syncthreads();
    if (t < SNUM)
        s_dist[t] = (s_part[t][0] + s_part[t][1]) + (s_part[t][2] + s_part[t][3]);
    __syncthreads();

    // Top-3 by descending distance; strict '>' keeps the earliest index on
    // ties, matching jax.lax.top_k / torch.sort(stable descending) semantics.
    if (t == 0) {
        unsigned chosen = 0;
        for (int k = 0; k < KNN; ++k) {
            float best = -1.0f;
            int   bi   = 0;
            for (int s = 0; s < SNUM; ++s) {
                if (chosen & (1u << s)) continue;
                if (s_dist[s] > best) { best = s_dist[s]; bi = s; }
            }
            chosen |= (1u << bi);
            s_sel[k] = bi;
        }
    }
    __syncthreads();

    // Pass 2: gather the 3 selected rows (L2/L3-warm) and accumulate.
    const float4 e0 = *reinterpret_cast<const float4*>(emb + (size_t)s_sid[s_sel[0]] * HDIM + 4 * t);
    const float4 e1 = *reinterpret_cast<const float4*>(emb + (size_t)s_sid[s_sel[1]] * HDIM + 4 * t);
    const float4 e2 = *reinterpret_cast<const float4*>(emb + (size_t)s_sid[s_sel[2]] * HDIM + 4 * t);

    const float third = 1.0f / 3.0f;
    const float scale = 0.5f / 16.0f;

    const float ox = ((e0.x + e1.x + e2.x) * third + wv.x) * scale;
    const float oy = ((e0.y + e1.y + e2.y) * third + wv.y) * scale;
    const float oz = ((e0.z + e1.z + e2.z) * third + wv.z) * scale;
    const float ow = ((e0.w + e1.w + e2.w) * third + wv.w) * scale;

    float* op = out + (size_t)l * HDIM + 4 * t;
    atomicAdd(op + 0, ox);
    atomicAdd(op + 1, oy);
    atomicAdd(op + 2, oz);
    atomicAdd(op + 3, ow);
}

extern "C" void kernel_launch(void* const* d_in, const int* in_sizes, int n_in,
                              void* d_out, int out_size, void* d_ws, size_t ws_size,
                              hipStream_t stream) {
    const float* emb  = (const float*)d_in[0];
    const int*   wids = (const int*)d_in[1];
    const int*   sids = (const int*)d_in[2];
    float*       out  = (float*)d_out;

    const int n_words = in_sizes[1];   // L*W = 4096 workgroups

    hipMemsetAsync(d_out, 0, (size_t)out_size * sizeof(float), stream);
    sememe_knn_kernel<<<dim3(n_words), dim3(256), 0, stream>>>(emb, wids, sids, out);
}

// Round 3
// 107.573 us; speedup vs baseline: 1.1785x; 1.0477x over previous
//
#include <hip/hip_runtime.h>

// SememeEmbeddingKNN, 3-phase barrier-free decomposition.
//   emb      [V=50257, H=1024] f32
//   word_ids [L=256, W=16]     i32
//   sem_ids  [L=256, W=16, S=32] i32
//   out      [L, H] f32
//
// R2 -> R3: warm replays (67 MB HBM) ran the same 124 us as cold (288 MB)
// -> latency/concurrency-bound, not BW-bound. Split into:
//   A: one wave per (b,s) pair (131072 waves), 8 indep float4 loads each,
//      wave-local reduce, dist2 -> ws. Zero barriers.
//   B: one thread per b, top-3 (strict '>', earliest index on ties = jax),
//      writes [sid0,sid1,sid2,wid] per b -> ws.
//   C: block per (l, h/4 quarter), register accumulation, single store.
//      No atomics, no memset -> deterministic.

#define HDIM 1024
#define SNUM 32
#define WNUM 16
#define KNN  3

// ---------------- Phase A: distances ----------------
__global__ __launch_bounds__(256) void knn_dist_kernel(
    const float* __restrict__ emb,
    const int*   __restrict__ word_ids,
    const int*   __restrict__ sem_ids,
    float*       __restrict__ dist,
    int nj)
{
    const int wave = threadIdx.x >> 6;
    const int lane = threadIdx.x & 63;
    const int j    = blockIdx.x * 4 + wave;     // job = b*32 + s
    if (j >= nj) return;
    const int b    = j >> 5;

    const int wid = word_ids[b];
    const int sid = sem_ids[j];

    const float* wrow = emb + (size_t)wid * HDIM + 4 * lane;
    const float* srow = emb + (size_t)sid * HDIM + 4 * lane;

    // 8 independent float4 loads (64 B/lane from each row).
    const float4 w0 = *(const float4*)(wrow + 0);
    const float4 w1 = *(const float4*)(wrow + 256);
    const float4 w2 = *(const float4*)(wrow + 512);
    const float4 w3 = *(const float4*)(wrow + 768);
    const float4 s0 = *(const float4*)(srow + 0);
    const float4 s1 = *(const float4*)(srow + 256);
    const float4 s2 = *(const float4*)(srow + 512);
    const float4 s3 = *(const float4*)(srow + 768);

    float d = 0.0f;
    {
        float dx = s0.x - w0.x, dy = s0.y - w0.y, dz = s0.z - w0.z, dw = s0.w - w0.w;
        d += dx * dx + dy * dy + dz * dz + dw * dw;
    }
    {
        float dx = s1.x - w1.x, dy = s1.y - w1.y, dz = s1.z - w1.z, dw = s1.w - w1.w;
        d += dx * dx + dy * dy + dz * dz + dw * dw;
    }
    {
        float dx = s2.x - w2.x, dy = s2.y - w2.y, dz = s2.z - w2.z, dw = s2.w - w2.w;
        d += dx * dx + dy * dy + dz * dz + dw * dw;
    }
    {
        float dx = s3.x - w3.x, dy = s3.y - w3.y, dz = s3.z - w3.z, dw = s3.w - w3.w;
        d += dx * dx + dy * dy + dz * dz + dw * dw;
    }

    #pragma unroll
    for (int off = 32; off >= 1; off >>= 1)
        d += __shfl_xor(d, off, 64);

    if (lane == 0) dist[j] = d;
}

// ---------------- Phase B: top-3 select ----------------
__global__ __launch_bounds__(256) void knn_select_kernel(
    const float* __restrict__ dist,
    const int*   __restrict__ word_ids,
    const int*   __restrict__ sem_ids,
    int*         __restrict__ sel,
    int nb)
{
    const int b = blockIdx.x * 256 + threadIdx.x;
    if (b >= nb) return;

    float dl[SNUM];
    #pragma unroll
    for (int s = 0; s < SNUM; ++s) dl[s] = dist[b * SNUM + s];

    unsigned chosen = 0;
    #pragma unroll
    for (int k = 0; k < KNN; ++k) {
        float best = -1.0f;
        int   bi   = 0;
        #pragma unroll
        for (int s = 0; s < SNUM; ++s) {
            if (!((chosen >> s) & 1u) && dl[s] > best) { best = dl[s]; bi = s; }
        }
        chosen |= (1u << bi);
        sel[b * 4 + k] = sem_ids[b * SNUM + bi];
    }
    sel[b * 4 + 3] = word_ids[b];
}

// ---------------- Phase C: gather + accumulate ----------------
__global__ __launch_bounds__(256) void knn_out_kernel(
    const float* __restrict__ emb,
    const int*   __restrict__ sel,
    float*       __restrict__ out)
{
    const int l = blockIdx.x >> 2;       // label
    const int q = blockIdx.x & 3;        // h-quarter
    const int h = q * 256 + threadIdx.x;

    __shared__ int s_ids[WNUM * 4];
    if (threadIdx.x < WNUM * 4) s_ids[threadIdx.x] = sel[l * WNUM * 4 + threadIdx.x];
    __syncthreads();

    const float third = 1.0f / 3.0f;
    float acc = 0.0f;
    #pragma unroll
    for (int w = 0; w < WNUM; ++w) {
        const float e0 = emb[(size_t)s_ids[w * 4 + 0] * HDIM + h];
        const float e1 = emb[(size_t)s_ids[w * 4 + 1] * HDIM + h];
        const float e2 = emb[(size_t)s_ids[w * 4 + 2] * HDIM + h];
        const float ew = emb[(size_t)s_ids[w * 4 + 3] * HDIM + h];
        acc += (e0 + e1 + e2) * third + ew;
    }
    out[(size_t)l * HDIM + h] = acc * (0.5f / 16.0f);
}

extern "C" void kernel_launch(void* const* d_in, const int* in_sizes, int n_in,
                              void* d_out, int out_size, void* d_ws, size_t ws_size,
                              hipStream_t stream) {
    const float* emb  = (const float*)d_in[0];
    const int*   wids = (const int*)d_in[1];
    const int*   sids = (const int*)d_in[2];
    float*       out  = (float*)d_out;

    const int nb = in_sizes[1];          // L*W = 4096
    const int nj = in_sizes[2];          // L*W*S = 131072
    const int L  = out_size / HDIM;      // 256

    float* dist = (float*)d_ws;                          // nj floats (512 KB)
    int*   sel  = (int*)((char*)d_ws + (size_t)nj * 4);  // nb*4 ints (64 KB)

    knn_dist_kernel<<<dim3((nj + 3) / 4), dim3(256), 0, stream>>>(emb, wids, sids, dist, nj);
    knn_select_kernel<<<dim3((nb + 255) / 256), dim3(256), 0, stream>>>(dist, wids, sids, sel, nb);
    knn_out_kernel<<<dim3(L * 4), dim3(256), 0, stream>>>(emb, sel, out);
}

// Round 4
// 95.270 us; speedup vs baseline: 1.3307x; 1.1291x over previous
//
#include <hip/hip_runtime.h>

// SememeEmbeddingKNN, 3-phase barrier-free decomposition.
//   emb      [V=50257, H=1024] f32
//   word_ids [L=256, W=16]     i32
//   sem_ids  [L=256, W=16, S=32] i32
//   out      [L, H] f32
//
// R3 -> R4: phase A was cache-BW-bound on LOGICAL bytes (1.07 GB: word row
// re-read per sememe). Now one wave per (b, sememe-quad): word row loaded
// once per wave (reused for 4 sememes) -> logical traffic 0.65 GB, and 20
// independent float4 loads in flight per wave (was 8).

#define HDIM 1024
#define SNUM 32
#define WNUM 16
#define KNN  3

// ---------------- Phase A: distances (wave per 4-sememe quad) ----------------
__global__ __launch_bounds__(256) void knn_dist_kernel(
    const float* __restrict__ emb,
    const int*   __restrict__ word_ids,
    const int*   __restrict__ sem_ids,
    float*       __restrict__ dist,
    int nq)                                  // nq = nb * 8 quads
{
    const int wave = threadIdx.x >> 6;
    const int lane = threadIdx.x & 63;
    const int q    = blockIdx.x * 4 + wave;  // quad index = b*8 + quad
    if (q >= nq) return;
    const int b    = q >> 3;
    const int j0   = q * 4;                  // first job (b*32 + quad*4)

    const int wid  = word_ids[b];
    const int sid0 = sem_ids[j0 + 0];
    const int sid1 = sem_ids[j0 + 1];
    const int sid2 = sem_ids[j0 + 2];
    const int sid3 = sem_ids[j0 + 3];

    const float* wrow = emb + (size_t)wid * HDIM + 4 * lane;

    // Word row: 4 independent float4 (64 B/lane, whole 1024-row per wave).
    const float4 w0 = *(const float4*)(wrow + 0);
    const float4 w1 = *(const float4*)(wrow + 256);
    const float4 w2 = *(const float4*)(wrow + 512);
    const float4 w3 = *(const float4*)(wrow + 768);

    float d[4];
    const int sids[4] = {sid0, sid1, sid2, sid3};
    #pragma unroll
    for (int k = 0; k < 4; ++k) {
        const float* srow = emb + (size_t)sids[k] * HDIM + 4 * lane;
        const float4 s0 = *(const float4*)(srow + 0);
        const float4 s1 = *(const float4*)(srow + 256);
        const float4 s2 = *(const float4*)(srow + 512);
        const float4 s3 = *(const float4*)(srow + 768);
        float acc;
        {
            float dx = s0.x - w0.x, dy = s0.y - w0.y, dz = s0.z - w0.z, dw = s0.w - w0.w;
            acc = dx * dx + dy * dy + dz * dz + dw * dw;
        }
        {
            float dx = s1.x - w1.x, dy = s1.y - w1.y, dz = s1.z - w1.z, dw = s1.w - w1.w;
            acc += dx * dx + dy * dy + dz * dz + dw * dw;
        }
        {
            float dx = s2.x - w2.x, dy = s2.y - w2.y, dz = s2.z - w2.z, dw = s2.w - w2.w;
            acc += dx * dx + dy * dy + dz * dz + dw * dw;
        }
        {
            float dx = s3.x - w3.x, dy = s3.y - w3.y, dz = s3.z - w3.z, dw = s3.w - w3.w;
            acc += dx * dx + dy * dy + dz * dz + dw * dw;
        }
        d[k] = acc;
    }

    // 4 independent 6-deep shuffle-reduce chains (pipelined).
    #pragma unroll
    for (int k = 0; k < 4; ++k) {
        #pragma unroll
        for (int off = 32; off >= 1; off >>= 1)
            d[k] += __shfl_xor(d[k], off, 64);
    }

    if (lane == 0)
        *(float4*)(dist + j0) = make_float4(d[0], d[1], d[2], d[3]);
}

// ---------------- Phase B: top-3 select ----------------
__global__ __launch_bounds__(256) void knn_select_kernel(
    const float* __restrict__ dist,
    const int*   __restrict__ word_ids,
    const int*   __restrict__ sem_ids,
    int*         __restrict__ sel,
    int nb)
{
    const int b = blockIdx.x * 256 + threadIdx.x;
    if (b >= nb) return;

    float dl[SNUM];
    #pragma unroll
    for (int s = 0; s < SNUM; ++s) dl[s] = dist[b * SNUM + s];

    unsigned chosen = 0;
    #pragma unroll
    for (int k = 0; k < KNN; ++k) {
        float best = -1.0f;
        int   bi   = 0;
        #pragma unroll
        for (int s = 0; s < SNUM; ++s) {
            if (!((chosen >> s) & 1u) && dl[s] > best) { best = dl[s]; bi = s; }
        }
        chosen |= (1u << bi);
        sel[b * 4 + k] = sem_ids[b * SNUM + bi];
    }
    sel[b * 4 + 3] = word_ids[b];
}

// ---------------- Phase C: gather + accumulate ----------------
__global__ __launch_bounds__(256) void knn_out_kernel(
    const float* __restrict__ emb,
    const int*   __restrict__ sel,
    float*       __restrict__ out)
{
    const int l = blockIdx.x >> 2;       // label
    const int q = blockIdx.x & 3;        // h-quarter
    const int h = q * 256 + threadIdx.x;

    __shared__ int s_ids[WNUM * 4];
    if (threadIdx.x < WNUM * 4) s_ids[threadIdx.x] = sel[l * WNUM * 4 + threadIdx.x];
    __syncthreads();

    const float third = 1.0f / 3.0f;
    float acc = 0.0f;
    #pragma unroll
    for (int w = 0; w < WNUM; ++w) {
        const float e0 = emb[(size_t)s_ids[w * 4 + 0] * HDIM + h];
        const float e1 = emb[(size_t)s_ids[w * 4 + 1] * HDIM + h];
        const float e2 = emb[(size_t)s_ids[w * 4 + 2] * HDIM + h];
        const float ew = emb[(size_t)s_ids[w * 4 + 3] * HDIM + h];
        acc += (e0 + e1 + e2) * third + ew;
    }
    out[(size_t)l * HDIM + h] = acc * (0.5f / 16.0f);
}

extern "C" void kernel_launch(void* const* d_in, const int* in_sizes, int n_in,
                              void* d_out, int out_size, void* d_ws, size_t ws_size,
                              hipStream_t stream) {
    const float* emb  = (const float*)d_in[0];
    const int*   wids = (const int*)d_in[1];
    const int*   sids = (const int*)d_in[2];
    float*       out  = (float*)d_out;

    const int nb = in_sizes[1];          // L*W = 4096
    const int nj = in_sizes[2];          // L*W*S = 131072
    const int nq = nj / 4;               // 32768 quads
    const int L  = out_size / HDIM;      // 256

    float* dist = (float*)d_ws;                          // nj floats (512 KB)
    int*   sel  = (int*)((char*)d_ws + (size_t)nj * 4);  // nb*4 ints (64 KB)

    knn_dist_kernel<<<dim3((nq + 3) / 4), dim3(256), 0, stream>>>(emb, wids, sids, dist, nq);
    knn_select_kernel<<<dim3((nb + 255) / 256), dim3(256), 0, stream>>>(dist, wids, sids, sel, nb);
    knn_out_kernel<<<dim3(L * 4), dim3(256), 0, stream>>>(emb, sel, out);
}

// Round 5
// 91.570 us; speedup vs baseline: 1.3844x; 1.0404x over previous
//
#include <hip/hip_runtime.h>

// SememeEmbeddingKNN, 3-phase barrier-free decomposition.
//   emb      [V=50257, H=1024] f32   (206 MB -> L3-resident, L2-thin)
//   word_ids [L=256, W=16]     i32
//   sem_ids  [L=256, W=16, S=32] i32
//   out      [L, H] f32
//
// R4 -> R5: phase A efficiency dropped with the 20-load quad version
// (4 waves/SIMD). New mapping: one wave per (b, sememe-OCTET, QUARTER-row).
// lane owns one float4 of a 256-float quarter -> 9 row loads + 2 sid loads
// per wave, ~60 VGPR -> 8 waves/SIMD, 65536 waves. Word row amortized 8x:
// logical 590 MB. Quarter partial dists -> ws; select kernel sums quarters.

#define HDIM 1024
#define SNUM 32
#define WNUM 16
#define KNN  3

// ---------------- Phase A: partial distances (wave per b,octet,quarter) ----
__global__ __launch_bounds__(256) void knn_dist_kernel(
    const float* __restrict__ emb,
    const int*   __restrict__ word_ids,
    const int*   __restrict__ sem_ids,
    float*       __restrict__ dist_part,   // [4][nj]
    int nj)
{
    const int wave = threadIdx.x >> 6;     // octet 0..3
    const int lane = threadIdx.x & 63;
    const int blk  = blockIdx.x;           // b*4 + quarter
    const int b    = blk >> 2;
    const int quarter = blk & 3;

    const int base_s = b * SNUM + wave * 8;
    const int col    = quarter * 256 + 4 * lane;

    // 8 sememe ids via two int4 (32-B aligned), word id.
    const int4 sa = *(const int4*)(sem_ids + base_s);
    const int4 sb = *(const int4*)(sem_ids + base_s + 4);
    const int  wid = word_ids[b];

    const float4 w = *(const float4*)(emb + (size_t)wid * HDIM + col);

    const int sids[8] = {sa.x, sa.y, sa.z, sa.w, sb.x, sb.y, sb.z, sb.w};
    float4 sv[8];
    #pragma unroll
    for (int k = 0; k < 8; ++k)
        sv[k] = *(const float4*)(emb + (size_t)sids[k] * HDIM + col);

    #pragma unroll
    for (int k = 0; k < 8; ++k) {
        const float dx = sv[k].x - w.x;
        const float dy = sv[k].y - w.y;
        const float dz = sv[k].z - w.z;
        const float dw = sv[k].w - w.w;
        float d = (dx * dx + dy * dy) + (dz * dz + dw * dw);
        #pragma unroll
        for (int off = 32; off >= 1; off >>= 1)
            d += __shfl_xor(d, off, 64);
        if (lane == 0)
            dist_part[(size_t)quarter * nj + base_s + k] = d;
    }
}

// ---------------- Phase B: sum quarters + top-3 select ----------------
__global__ __launch_bounds__(256) void knn_select_kernel(
    const float* __restrict__ dist_part,   // [4][nj]
    const int*   __restrict__ word_ids,
    const int*   __restrict__ sem_ids,
    int*         __restrict__ sel,
    int nb, int nj)
{
    const int b = blockIdx.x * 256 + threadIdx.x;
    if (b >= nb) return;

    float4 acc[8];
    #pragma unroll
    for (int i = 0; i < 8; ++i) acc[i] = make_float4(0.f, 0.f, 0.f, 0.f);

    #pragma unroll
    for (int q = 0; q < 4; ++q) {
        const float4* p = (const float4*)(dist_part + (size_t)q * nj + b * SNUM);
        #pragma unroll
        for (int i = 0; i < 8; ++i) {
            const float4 v = p[i];
            acc[i].x += v.x; acc[i].y += v.y; acc[i].z += v.z; acc[i].w += v.w;
        }
    }

    float dl[SNUM];
    #pragma unroll
    for (int i = 0; i < 8; ++i) {
        dl[4 * i + 0] = acc[i].x;
        dl[4 * i + 1] = acc[i].y;
        dl[4 * i + 2] = acc[i].z;
        dl[4 * i + 3] = acc[i].w;
    }

    // Top-3 descending; strict '>' keeps earliest index on ties (= jax top_k).
    unsigned chosen = 0;
    #pragma unroll
    for (int k = 0; k < KNN; ++k) {
        float best = -1.0f;
        int   bi   = 0;
        #pragma unroll
        for (int s = 0; s < SNUM; ++s) {
            if (!((chosen >> s) & 1u) && dl[s] > best) { best = dl[s]; bi = s; }
        }
        chosen |= (1u << bi);
        sel[b * 4 + k] = sem_ids[b * SNUM + bi];
    }
    sel[b * 4 + 3] = word_ids[b];
}

// ---------------- Phase C: gather + accumulate ----------------
__global__ __launch_bounds__(256) void knn_out_kernel(
    const float* __restrict__ emb,
    const int*   __restrict__ sel,
    float*       __restrict__ out)
{
    const int l = blockIdx.x >> 2;       // label
    const int q = blockIdx.x & 3;        // h-quarter
    const int h = q * 256 + threadIdx.x;

    __shared__ int s_ids[WNUM * 4];
    if (threadIdx.x < WNUM * 4) s_ids[threadIdx.x] = sel[l * WNUM * 4 + threadIdx.x];
    __syncthreads();

    const float third = 1.0f / 3.0f;
    float acc = 0.0f;
    #pragma unroll
    for (int w = 0; w < WNUM; ++w) {
        const float e0 = emb[(size_t)s_ids[w * 4 + 0] * HDIM + h];
        const float e1 = emb[(size_t)s_ids[w * 4 + 1] * HDIM + h];
        const float e2 = emb[(size_t)s_ids[w * 4 + 2] * HDIM + h];
        const float ew = emb[(size_t)s_ids[w * 4 + 3] * HDIM + h];
        acc += (e0 + e1 + e2) * third + ew;
    }
    out[(size_t)l * HDIM + h] = acc * (0.5f / 16.0f);
}

extern "C" void kernel_launch(void* const* d_in, const int* in_sizes, int n_in,
                              void* d_out, int out_size, void* d_ws, size_t ws_size,
                              hipStream_t stream) {
    const float* emb  = (const float*)d_in[0];
    const int*   wids = (const int*)d_in[1];
    const int*   sids = (const int*)d_in[2];
    float*       out  = (float*)d_out;

    const int nb = in_sizes[1];          // L*W = 4096
    const int nj = in_sizes[2];          // L*W*S = 131072
    const int L  = out_size / HDIM;      // 256

    float* dist_part = (float*)d_ws;                            // 4*nj floats (2 MB)
    int*   sel       = (int*)((char*)d_ws + (size_t)4 * nj * 4); // nb*4 ints

    knn_dist_kernel<<<dim3(nb * 4), dim3(256), 0, stream>>>(emb, wids, sids, dist_part, nj);
    knn_select_kernel<<<dim3((nb + 255) / 256), dim3(256), 0, stream>>>(dist_part, wids, sids, sel, nb, nj);
    knn_out_kernel<<<dim3(L * 4), dim3(256), 0, stream>>>(emb, sel, out);
}

// Round 6
// 90.185 us; speedup vs baseline: 1.4057x; 1.0154x over previous
//
#include <hip/hip_runtime.h>

// SememeEmbeddingKNN, 2-kernel decomposition.
//   emb      [V=50257, H=1024] f32   (206 MB -> L3-resident, L2-thin)
//   word_ids [L=256, W=16]     i32
//   sem_ids  [L=256, W=16, S=32] i32
//   out      [L, H] f32
//
// R5 -> R6:
//  A: wave per (b, octet, quarter) as before, but word quarter staged in LDS
//     once per block (was 4x redundant), dist writes as 2x float4 (was 8
//     scalar stores).
//  BC (fused): block per label l. Stage 1: threads 0..15 sum the 4 quarter
//     partials and do the top-3 (strict '>', earliest index on ties = jax).
//     Stage 2: all 256 threads gather with float4 (16 B/lane, was 4 B/lane)
//     and write out[l]. No atomics, no memset.

#define HDIM 1024
#define SNUM 32
#define WNUM 16
#define KNN  3

// ---------------- Phase A: partial distances (wave per b,octet,quarter) ----
__global__ __launch_bounds__(256) void knn_dist_kernel(
    const float* __restrict__ emb,
    const int*   __restrict__ word_ids,
    const int*   __restrict__ sem_ids,
    float*       __restrict__ dist_part,   // [4][nj]
    int nj)
{
    const int wave = threadIdx.x >> 6;     // octet 0..3
    const int lane = threadIdx.x & 63;
    const int blk  = blockIdx.x;           // b*4 + quarter
    const int b    = blk >> 2;
    const int quarter = blk & 3;

    __shared__ float s_w[256];

    const int wid = word_ids[b];
    // Coop word-quarter load: 1 float/thread.
    s_w[threadIdx.x] = emb[(size_t)wid * HDIM + quarter * 256 + threadIdx.x];

    const int base_s = b * SNUM + wave * 8;
    const int col    = quarter * 256 + 4 * lane;

    // 8 sememe ids via two int4.
    const int4 sa = *(const int4*)(sem_ids + base_s);
    const int4 sb = *(const int4*)(sem_ids + base_s + 4);

    __syncthreads();
    const float4 w = *(const float4*)(s_w + 4 * lane);

    const int sids[8] = {sa.x, sa.y, sa.z, sa.w, sb.x, sb.y, sb.z, sb.w};
    float4 sv[8];
    #pragma unroll
    for (int k = 0; k < 8; ++k)
        sv[k] = *(const float4*)(emb + (size_t)sids[k] * HDIM + col);

    float d[8];
    #pragma unroll
    for (int k = 0; k < 8; ++k) {
        const float dx = sv[k].x - w.x;
        const float dy = sv[k].y - w.y;
        const float dz = sv[k].z - w.z;
        const float dw = sv[k].w - w.w;
        d[k] = (dx * dx + dy * dy) + (dz * dz + dw * dw);
    }

    // 8 independent 6-deep shuffle-reduce chains (pipelined).
    #pragma unroll
    for (int k = 0; k < 8; ++k) {
        #pragma unroll
        for (int off = 32; off >= 1; off >>= 1)
            d[k] += __shfl_xor(d[k], off, 64);
    }

    if (lane == 0) {
        float* p = dist_part + (size_t)quarter * nj + base_s;
        *(float4*)(p + 0) = make_float4(d[0], d[1], d[2], d[3]);
        *(float4*)(p + 4) = make_float4(d[4], d[5], d[6], d[7]);
    }
}

// ------------- Phase BC: select (top-3) + gather/accumulate, fused --------
__global__ __launch_bounds__(256) void knn_outsel_kernel(
    const float* __restrict__ emb,
    const float* __restrict__ dist_part,   // [4][nj]
    const int*   __restrict__ word_ids,
    const int*   __restrict__ sem_ids,
    float*       __restrict__ out,
    int nj)
{
    const int l = blockIdx.x;
    const int t = threadIdx.x;

    __shared__ int s_ids[WNUM * 4];

    // Stage 1: threads 0..15 each select for one word.
    if (t < WNUM) {
        const int b = l * WNUM + t;
        float4 acc[8];
        #pragma unroll
        for (int i = 0; i < 8; ++i) acc[i] = make_float4(0.f, 0.f, 0.f, 0.f);
        #pragma unroll
        for (int q = 0; q < 4; ++q) {
            const float4* p = (const float4*)(dist_part + (size_t)q * nj + b * SNUM);
            #pragma unroll
            for (int i = 0; i < 8; ++i) {
                const float4 v = p[i];
                acc[i].x += v.x; acc[i].y += v.y; acc[i].z += v.z; acc[i].w += v.w;
            }
        }
        float dl[SNUM];
        #pragma unroll
        for (int i = 0; i < 8; ++i) {
            dl[4 * i + 0] = acc[i].x;
            dl[4 * i + 1] = acc[i].y;
            dl[4 * i + 2] = acc[i].z;
            dl[4 * i + 3] = acc[i].w;
        }
        // Top-3 descending; strict '>' keeps earliest index (= jax top_k).
        unsigned chosen = 0;
        #pragma unroll
        for (int k = 0; k < KNN; ++k) {
            float best = -1.0f;
            int   bi   = 0;
            #pragma unroll
            for (int s = 0; s < SNUM; ++s) {
                if (!((chosen >> s) & 1u) && dl[s] > best) { best = dl[s]; bi = s; }
            }
            chosen |= (1u << bi);
            s_ids[t * 4 + k] = sem_ids[b * SNUM + bi];
        }
        s_ids[t * 4 + 3] = word_ids[b];
    }
    __syncthreads();

    // Stage 2: all 256 threads gather float4 at h = 4t.
    const float third = 1.0f / 3.0f;
    float ax = 0.f, ay = 0.f, az = 0.f, aw = 0.f;
    #pragma unroll 4
    for (int w = 0; w < WNUM; ++w) {
        const float4 e0 = *(const float4*)(emb + (size_t)s_ids[w * 4 + 0] * HDIM + 4 * t);
        const float4 e1 = *(const float4*)(emb + (size_t)s_ids[w * 4 + 1] * HDIM + 4 * t);
        const float4 e2 = *(const float4*)(emb + (size_t)s_ids[w * 4 + 2] * HDIM + 4 * t);
        const float4 ew = *(const float4*)(emb + (size_t)s_ids[w * 4 + 3] * HDIM + 4 * t);
        ax += (e0.x + e1.x + e2.x) * third + ew.x;
        ay += (e0.y + e1.y + e2.y) * third + ew.y;
        az += (e0.z + e1.z + e2.z) * third + ew.z;
        aw += (e0.w + e1.w + e2.w) * third + ew.w;
    }
    const float scale = 0.5f / 16.0f;
    *(float4*)(out + (size_t)l * HDIM + 4 * t) =
        make_float4(ax * scale, ay * scale, az * scale, aw * scale);
}

extern "C" void kernel_launch(void* const* d_in, const int* in_sizes, int n_in,
                              void* d_out, int out_size, void* d_ws, size_t ws_size,
                              hipStream_t stream) {
    const float* emb  = (const float*)d_in[0];
    const int*   wids = (const int*)d_in[1];
    const int*   sids = (const int*)d_in[2];
    float*       out  = (float*)d_out;

    const int nb = in_sizes[1];          // L*W = 4096
    const int nj = in_sizes[2];          // L*W*S = 131072
    const int L  = out_size / HDIM;      // 256

    float* dist_part = (float*)d_ws;     // 4*nj floats (2 MB)

    knn_dist_kernel<<<dim3(nb * 4), dim3(256), 0, stream>>>(emb, wids, sids, dist_part, nj);
    knn_outsel_kernel<<<dim3(L), dim3(256), 0, stream>>>(emb, dist_part, wids, sids, out, nj);
}